// Round 7
// baseline (398.698 us; speedup 1.0000x reference)
//
#include <hip/hip_runtime.h>
#include <math.h>

// ODCMemory.update_samples_memory for MI355X (gfx950) — split-kernel version
// d_in[0] feature_bank [L,D] f32   d_in[1] label_bank [L] int32
// d_in[2] centroids   [C,D] f32    d_in[3] ind [B] int32
// d_in[4] feature     [B,D] f32
// d_out f32: new_bank [L*D] | new_labels [L] | change_ratio [1]

constexpr int Lb = 500000;
constexpr int Dm = 256;
constexpr int D4 = 64;          // float4 per row
constexpr int Cc = 1024;
constexpr int Bb = 16384;
constexpr float EPSV = 1e-10f;

constexpr int ROWS  = 8;                // batch rows per classify block
constexpr int GCLS  = Bb / ROWS;        // 2048 classify blocks
constexpr int GCPY  = 3072;             // copy blocks
constexpr int GPRE  = 1024;
constexpr int GPOST = 1024;

typedef float vfloat4 __attribute__((ext_vector_type(4)));  // native vec for NT stores

__device__ __forceinline__ float wave_sum64(float v) {
#pragma unroll
  for (int off = 32; off > 0; off >>= 1) v += __shfl_xor(v, off);
  return v;
}

// momentum-normalized feature for batch row gb vs bank row bankrow (lane = float4 slice)
__device__ __forceinline__ float4 feat_new_row(const float4* __restrict__ feat4,
                                               const float4* __restrict__ bank4,
                                               int gb, int bankrow, int lane) {
  float4 f = feat4[(size_t)gb * D4 + lane];
  const float ss = wave_sum64(f.x * f.x + f.y * f.y + f.z * f.z + f.w * f.w);
  const float inv1 = 1.0f / (sqrtf(ss) + EPSV);
  const float4 o = bank4[(size_t)bankrow * D4 + lane];
  float4 nw;
  nw.x = 0.5f * o.x + 0.5f * (f.x * inv1);
  nw.y = 0.5f * o.y + 0.5f * (f.y * inv1);
  nw.z = 0.5f * o.z + 0.5f * (f.z * inv1);
  nw.w = 0.5f * o.w + 0.5f * (f.w * inv1);
  const float s2 = wave_sum64(nw.x * nw.x + nw.y * nw.y + nw.z * nw.z + nw.w * nw.w);
  const float inv2 = 1.0f / (sqrtf(s2) + EPSV);
  nw.x *= inv2; nw.y *= inv2; nw.z *= inv2; nw.w *= inv2;
  return nw;
}

// marker clear + count clear + centroid transpose + feat_new precompute
__global__ __launch_bounds__(256)
void k_pre(const float4* __restrict__ feat4, const float4* __restrict__ bank4,
           const int* __restrict__ ind, const float* __restrict__ cent,
           float* __restrict__ centT, float4* __restrict__ fnew4,
           int* __restrict__ marker, int* __restrict__ count) {
  const int tid = threadIdx.x, lane = tid & 63, wv = tid >> 6;
  const int t = blockIdx.x * 256 + tid;
  const int stride = GPRE * 256;
  for (int i = t; i < Lb; i += stride) marker[i] = -1;
  for (int i = t; i < Cc * Dm; i += stride) {
    const int d = i >> 10, c = i & (Cc - 1);
    centT[i] = cent[c * Dm + d];          // centT[d][c]; coalesced write
  }
  if (t == 0) *count = 0;
  const int w = blockIdx.x * 4 + wv;      // 4096 waves, 4 rows each
  for (int b = w; b < Bb; b += GPRE * 4)
    fnew4[(size_t)b * D4 + lane] = feat_new_row(feat4, bank4, b, ind[b], lane);
}

__global__ void k_mark(const int* __restrict__ ind, int* __restrict__ marker) {
  const int b = blockIdx.x * blockDim.x + threadIdx.x;
  if (b < Bb) atomicMax(&marker[ind[b]], b);
}

// 8 batch rows vs all 1024 centroids; thread owns 4 consecutive centroids.
// Simple loop, low VGPR -> high occupancy; TLP hides L2/LDS latency.
__global__ __launch_bounds__(256)
void k_classify(const float4* __restrict__ centT4, const float4* __restrict__ fnew4,
                const int* __restrict__ ind, const int* __restrict__ label_bank,
                int* __restrict__ newlabel, int* __restrict__ count) {
  __shared__ float4 fs[ROWS][D4];      // 8 KB feat tile
  __shared__ float  redv[ROWS][4];
  __shared__ int    redc[ROWS][4];
  const int tid = threadIdx.x, lane = tid & 63, wv = tid >> 6;
  const int b0  = (int)blockIdx.x * ROWS;
  const int c0  = tid * 4;             // this thread's 4 centroids

  for (int k = tid; k < ROWS * D4; k += 256)
    ((float4*)fs)[k] = fnew4[(size_t)b0 * D4 + k];
  __syncthreads();

  float4 acc[ROWS];
#pragma unroll
  for (int r = 0; r < ROWS; ++r) acc[r] = make_float4(0.f, 0.f, 0.f, 0.f);

  const float4* __restrict__ cvp = centT4 + tid;   // centT4[d*256 + tid]

  for (int d4 = 0; d4 < D4; ++d4) {
    const float4 cv0 = cvp[(size_t)(d4 * 4 + 0) * 256];   // coalesced 1KB/wave
    const float4 cv1 = cvp[(size_t)(d4 * 4 + 1) * 256];
    const float4 cv2 = cvp[(size_t)(d4 * 4 + 2) * 256];
    const float4 cv3 = cvp[(size_t)(d4 * 4 + 3) * 256];
#pragma unroll
    for (int r = 0; r < ROWS; ++r) {
      const float4 f = fs[r][d4];                         // LDS broadcast (conflict-free)
      acc[r].x = fmaf(cv0.x, f.x, acc[r].x);
      acc[r].y = fmaf(cv0.y, f.x, acc[r].y);
      acc[r].z = fmaf(cv0.z, f.x, acc[r].z);
      acc[r].w = fmaf(cv0.w, f.x, acc[r].w);
      acc[r].x = fmaf(cv1.x, f.y, acc[r].x);
      acc[r].y = fmaf(cv1.y, f.y, acc[r].y);
      acc[r].z = fmaf(cv1.z, f.y, acc[r].z);
      acc[r].w = fmaf(cv1.w, f.y, acc[r].w);
      acc[r].x = fmaf(cv2.x, f.z, acc[r].x);
      acc[r].y = fmaf(cv2.y, f.z, acc[r].y);
      acc[r].z = fmaf(cv2.z, f.z, acc[r].z);
      acc[r].w = fmaf(cv2.w, f.z, acc[r].w);
      acc[r].x = fmaf(cv3.x, f.w, acc[r].x);
      acc[r].y = fmaf(cv3.y, f.w, acc[r].y);
      acc[r].z = fmaf(cv3.z, f.w, acc[r].z);
      acc[r].w = fmaf(cv3.w, f.w, acc[r].w);
    }
  }

  // per-row argmax: within-thread (ascending idx, strict >), cross-lane, cross-wave
#pragma unroll
  for (int r = 0; r < ROWS; ++r) {
    float v = acc[r].x; int c = c0;
    if (acc[r].y > v) { v = acc[r].y; c = c0 + 1; }
    if (acc[r].z > v) { v = acc[r].z; c = c0 + 2; }
    if (acc[r].w > v) { v = acc[r].w; c = c0 + 3; }
#pragma unroll
    for (int off = 32; off > 0; off >>= 1) {
      const float ov = __shfl_xor(v, off);
      const int   oc = __shfl_xor(c, off);
      if (ov > v || (ov == v && oc < c)) { v = ov; c = oc; }
    }
    if (lane == 0) { redv[r][wv] = v; redc[r][wv] = c; }
  }
  __syncthreads();
  if (tid < ROWS) {
    const int r = tid;
    float v = redv[r][0]; int c = redc[r][0];
#pragma unroll
    for (int w = 1; w < 4; ++w) {
      const float ov = redv[r][w]; const int oc = redc[r][w];
      if (ov > v || (ov == v && oc < c)) { v = ov; c = oc; }
    }
    const int gb = b0 + r;
    newlabel[gb] = c;
    if (c != label_bank[ind[gb]]) atomicAdd(count, 1);
  }
}

// pure streaming copy of the whole bank; NT stores (out is never re-read)
__global__ __launch_bounds__(256)
void k_copy(const vfloat4* __restrict__ src, vfloat4* __restrict__ dst) {
  const size_t stride = (size_t)GCPY * 256;
  const size_t n4 = (size_t)Lb * D4;
  size_t i = (size_t)blockIdx.x * 256 + threadIdx.x;
  for (; i + 3 * stride < n4; i += 4 * stride) {
    const vfloat4 a = src[i];
    const vfloat4 b = src[i + stride];
    const vfloat4 c = src[i + 2 * stride];
    const vfloat4 d = src[i + 3 * stride];
    __builtin_nontemporal_store(a, &dst[i]);
    __builtin_nontemporal_store(b, &dst[i + stride]);
    __builtin_nontemporal_store(c, &dst[i + 2 * stride]);
    __builtin_nontemporal_store(d, &dst[i + 3 * stride]);
  }
  for (; i < n4; i += stride) __builtin_nontemporal_store(src[i], &dst[i]);
}

// winner rows from fnew, labels, ratio
__global__ __launch_bounds__(256)
void k_post(const float4* __restrict__ fnew4, const int* __restrict__ ind,
            const int* __restrict__ marker, const int* __restrict__ newlabel,
            const int* __restrict__ label_bank, const int* __restrict__ count,
            float4* __restrict__ out4, float* __restrict__ out_lab,
            float* __restrict__ out_ratio) {
  const int tid = threadIdx.x, lane = tid & 63, wv = tid >> 6;
  const int t = blockIdx.x * 256 + tid;
  const int stride = GPOST * 256;
  for (int i = t; i < Lb; i += stride) {
    const int m = marker[i];
    out_lab[i] = (float)(m >= 0 ? newlabel[m] : label_bank[i]);
  }
  const int w = blockIdx.x * 4 + wv;
  for (int b = w; b < Bb; b += GPOST * 4) {
    const int r = ind[b];
    if (marker[r] == b) out4[(size_t)r * D4 + lane] = fnew4[(size_t)b * D4 + lane];
  }
  if (t == 0) *out_ratio = (float)(*count) / (float)Bb;
}

extern "C" void kernel_launch(void* const* d_in, const int* in_sizes, int n_in,
                              void* d_out, int out_size, void* d_ws, size_t ws_size,
                              hipStream_t stream) {
  const float* bank       = (const float*)d_in[0];
  const int*   label_bank = (const int*)  d_in[1];
  const float* cent       = (const float*)d_in[2];
  const int*   ind        = (const int*)  d_in[3];
  const float* feat       = (const float*)d_in[4];
  float* out = (float*)d_out;

  int*   marker   = (int*)d_ws;                  // [Lb]
  int*   newlabel = marker + Lb;                 // [Bb]
  int*   count    = newlabel + Bb;               // [1]
  float* centT    = (float*)(count + 1);         // [Dm*Cc]  1 MB
  float* fnew     = centT + (size_t)Dm * Cc;     // [Bb*Dm] 16 MB

  float* out_lab   = out + (size_t)Lb * Dm;
  float* out_ratio = out_lab + Lb;

  k_pre     <<<GPRE, 256, 0, stream>>>((const float4*)feat, (const float4*)bank, ind,
                                       cent, centT, (float4*)fnew, marker, count);
  k_mark    <<<Bb / 256, 256, 0, stream>>>(ind, marker);
  k_classify<<<GCLS, 256, 0, stream>>>((const float4*)centT, (const float4*)fnew,
                                       ind, label_bank, newlabel, count);
  k_copy    <<<GCPY, 256, 0, stream>>>((const vfloat4*)bank, (vfloat4*)out);
  k_post    <<<GPOST, 256, 0, stream>>>((const float4*)fnew, ind, marker, newlabel,
                                        label_bank, count, (float4*)out, out_lab, out_ratio);
}

// Round 8
// 284.034 us; speedup vs baseline: 1.4037x; 1.4037x over previous
//
#include <hip/hip_runtime.h>
#include <math.h>

// ODCMemory.update_samples_memory for MI355X (gfx950)
// d_in[0] feature_bank [L,D] f32   d_in[1] label_bank [L] int32
// d_in[2] centroids   [C,D] f32    d_in[3] ind [B] int32
// d_in[4] feature     [B,D] f32
// d_out f32: new_bank [L*D] | new_labels [L] | change_ratio [1]

constexpr int Lb = 500000;
constexpr int Dm = 256;
constexpr int D4 = 64;          // float4 per row
constexpr int Cc = 1024;
constexpr int Bb = 16384;
constexpr float EPSV = 1e-10f;

constexpr int ROWS_BLK = 16;            // rows per classify block (2 wave-pairs x 8)
constexpr int GCLS  = Bb / ROWS_BLK;    // 1024 classify blocks
constexpr int GCPY  = 2048;             // copy blocks
constexpr int GMAIN = GCLS + GCPY;      // 3072; bid%3==0 -> classify
constexpr int GPRE  = 1024;
constexpr int GPOST = 1024;

typedef float vfloat4 __attribute__((ext_vector_type(4)));  // native vec for NT ops

__device__ __forceinline__ float wave_sum64(float v) {
#pragma unroll
  for (int off = 32; off > 0; off >>= 1) v += __shfl_xor(v, off);
  return v;
}

// momentum-normalized feature for batch row gb vs bank row bankrow (lane = float4 slice)
__device__ __forceinline__ float4 feat_new_row(const float4* __restrict__ feat4,
                                               const float4* __restrict__ bank4,
                                               int gb, int bankrow, int lane) {
  float4 f = feat4[(size_t)gb * D4 + lane];
  const float ss = wave_sum64(f.x * f.x + f.y * f.y + f.z * f.z + f.w * f.w);
  const float inv1 = 1.0f / (sqrtf(ss) + EPSV);
  const float4 o = bank4[(size_t)bankrow * D4 + lane];
  float4 nw;
  nw.x = 0.5f * o.x + 0.5f * (f.x * inv1);
  nw.y = 0.5f * o.y + 0.5f * (f.y * inv1);
  nw.z = 0.5f * o.z + 0.5f * (f.z * inv1);
  nw.w = 0.5f * o.w + 0.5f * (f.w * inv1);
  const float s2 = wave_sum64(nw.x * nw.x + nw.y * nw.y + nw.z * nw.z + nw.w * nw.w);
  const float inv2 = 1.0f / (sqrtf(s2) + EPSV);
  nw.x *= inv2; nw.y *= inv2; nw.z *= inv2; nw.w *= inv2;
  return nw;
}

// marker clear + count clear + centroid transpose + feat_new precompute
__global__ __launch_bounds__(256)
void k_pre(const float4* __restrict__ feat4, const float4* __restrict__ bank4,
           const int* __restrict__ ind, const float* __restrict__ cent,
           float* __restrict__ centT, float4* __restrict__ fnew4,
           int* __restrict__ marker, int* __restrict__ count) {
  const int tid = threadIdx.x, lane = tid & 63, wv = tid >> 6;
  const int t = blockIdx.x * 256 + tid;
  const int stride = GPRE * 256;
  for (int i = t; i < Lb; i += stride) marker[i] = -1;
  for (int i = t; i < Cc * Dm; i += stride) {
    const int d = i >> 10, c = i & (Cc - 1);
    centT[i] = cent[c * Dm + d];          // centT[d][c]; coalesced write
  }
  if (t == 0) *count = 0;
  const int w = blockIdx.x * 4 + wv;      // 4096 waves, 4 rows each
  for (int b = w; b < Bb; b += GPRE * 4)
    fnew4[(size_t)b * D4 + lane] = feat_new_row(feat4, bank4, b, ind[b], lane);
}

__global__ void k_mark(const int* __restrict__ ind, int* __restrict__ marker) {
  const int b = blockIdx.x * blockDim.x + threadIdx.x;
  if (b < Bb) atomicMax(&marker[ind[b]], b);
}

__global__ __launch_bounds__(256, 3)
void k_main(const float4* __restrict__ bank4, const float4* __restrict__ centT4,
            const float4* __restrict__ fnew4, const int* __restrict__ ind,
            const int* __restrict__ label_bank,
            int* __restrict__ newlabel, int* __restrict__ count,
            float4* __restrict__ out4) {
  const int tid  = threadIdx.x;
  const int lane = tid & 63;
  const int wv   = tid >> 6;
  const int bid  = blockIdx.x;

  if (bid % 3 == 0) {
    // ---- classify: 16 rows x 1024 cents. wave-pair wp=wv>>1 owns 8 rows;
    //      within a pair, 128 threads own 8 cents each (hw=wv&1 -> cent half).
    __shared__ float4 fs[ROWS_BLK][D4];      // 16 KB feat tile
    __shared__ float  redv[ROWS_BLK][2];
    __shared__ int    redc[ROWS_BLK][2];
    const int cls = bid / 3;                 // 0..1023
    const int b0  = cls * ROWS_BLK;
    const int wp  = wv >> 1;                 // row-half
    const int cth = tid & 127;               // cent-thread 0..127
    const int c0  = cth * 8;                 // first of this thread's 8 cents

    for (int k = tid; k < ROWS_BLK * D4; k += 256)
      ((float4*)fs)[k] = fnew4[(size_t)b0 * D4 + k];
    __syncthreads();

    float4 a0[8], a1[8];                     // acc[row][cent-f4 0/1]
#pragma unroll
    for (int r = 0; r < 8; ++r) { a0[r] = make_float4(0,0,0,0); a1[r] = make_float4(0,0,0,0); }

    const float4* __restrict__ cvp = centT4 + cth * 2;   // centT4[d*256 + cth*2 (+1)]

    for (int d4 = 0; d4 < D4; ++d4) {
      float4 cva[4], cvb[4];
#pragma unroll
      for (int dd = 0; dd < 4; ++dd) {
        cva[dd] = cvp[(size_t)(d4 * 4 + dd) * 256];      // coalesced 2KB/wave
        cvb[dd] = cvp[(size_t)(d4 * 4 + dd) * 256 + 1];
      }
#pragma unroll
      for (int r = 0; r < 8; ++r) {
        const float4 f = fs[wp * 8 + r][d4];             // LDS broadcast
#pragma unroll
        for (int dd = 0; dd < 4; ++dd) {
          const float fv = (dd == 0) ? f.x : (dd == 1) ? f.y : (dd == 2) ? f.z : f.w;
          a0[r].x = fmaf(cva[dd].x, fv, a0[r].x);
          a0[r].y = fmaf(cva[dd].y, fv, a0[r].y);
          a0[r].z = fmaf(cva[dd].z, fv, a0[r].z);
          a0[r].w = fmaf(cva[dd].w, fv, a0[r].w);
          a1[r].x = fmaf(cvb[dd].x, fv, a1[r].x);
          a1[r].y = fmaf(cvb[dd].y, fv, a1[r].y);
          a1[r].z = fmaf(cvb[dd].z, fv, a1[r].z);
          a1[r].w = fmaf(cvb[dd].w, fv, a1[r].w);
        }
      }
    }

    // per-row argmax: fold 8 cents (ascending idx, strict >), cross-lane, cross-half
#pragma unroll
    for (int r = 0; r < 8; ++r) {
      float v = a0[r].x; int c = c0;
      if (a0[r].y > v) { v = a0[r].y; c = c0 + 1; }
      if (a0[r].z > v) { v = a0[r].z; c = c0 + 2; }
      if (a0[r].w > v) { v = a0[r].w; c = c0 + 3; }
      if (a1[r].x > v) { v = a1[r].x; c = c0 + 4; }
      if (a1[r].y > v) { v = a1[r].y; c = c0 + 5; }
      if (a1[r].z > v) { v = a1[r].z; c = c0 + 6; }
      if (a1[r].w > v) { v = a1[r].w; c = c0 + 7; }
#pragma unroll
      for (int off = 32; off > 0; off >>= 1) {
        const float ov = __shfl_xor(v, off);
        const int   oc = __shfl_xor(c, off);
        if (ov > v || (ov == v && oc < c)) { v = ov; c = oc; }
      }
      if (lane == 0) { redv[wp * 8 + r][wv & 1] = v; redc[wp * 8 + r][wv & 1] = c; }
    }
    __syncthreads();
    if (tid < ROWS_BLK) {
      float v = redv[tid][0]; int c = redc[tid][0];          // half 0 = smaller indices
      const float ov = redv[tid][1]; const int oc = redc[tid][1];
      if (ov > v) { v = ov; c = oc; }                        // strict > keeps smaller idx
      const int gb = b0 + tid;
      newlabel[gb] = c;
      if (c != label_bank[ind[gb]]) atomicAdd(count, 1);
    }
  } else {
    // ---- streaming copy of the whole bank; NT loads+stores keep L2 for centT ----
    const int cpy = (bid / 3) * 2 + (bid % 3) - 1;   // 0..2047
    const size_t stride = (size_t)GCPY * 256;
    const size_t n4 = (size_t)Lb * D4;
    const vfloat4* __restrict__ src = (const vfloat4*)bank4;
    vfloat4* __restrict__ dst = (vfloat4*)out4;
    size_t i = (size_t)cpy * 256 + tid;
    for (; i + 3 * stride < n4; i += 4 * stride) {
      const vfloat4 a = __builtin_nontemporal_load(&src[i]);
      const vfloat4 b = __builtin_nontemporal_load(&src[i + stride]);
      const vfloat4 c = __builtin_nontemporal_load(&src[i + 2 * stride]);
      const vfloat4 d = __builtin_nontemporal_load(&src[i + 3 * stride]);
      __builtin_nontemporal_store(a, &dst[i]);
      __builtin_nontemporal_store(b, &dst[i + stride]);
      __builtin_nontemporal_store(c, &dst[i + 2 * stride]);
      __builtin_nontemporal_store(d, &dst[i + 3 * stride]);
    }
    for (; i < n4; i += stride)
      __builtin_nontemporal_store(__builtin_nontemporal_load(&src[i]), &dst[i]);
  }
}

// winner rows from fnew, labels, ratio
__global__ __launch_bounds__(256)
void k_post(const float4* __restrict__ fnew4, const int* __restrict__ ind,
            const int* __restrict__ marker, const int* __restrict__ newlabel,
            const int* __restrict__ label_bank, const int* __restrict__ count,
            float4* __restrict__ out4, float* __restrict__ out_lab,
            float* __restrict__ out_ratio) {
  const int tid = threadIdx.x, lane = tid & 63, wv = tid >> 6;
  const int t = blockIdx.x * 256 + tid;
  const int stride = GPOST * 256;
  for (int i = t; i < Lb; i += stride) {
    const int m = marker[i];
    out_lab[i] = (float)(m >= 0 ? newlabel[m] : label_bank[i]);
  }
  const int w = blockIdx.x * 4 + wv;
  for (int b = w; b < Bb; b += GPOST * 4) {
    const int r = ind[b];
    if (marker[r] == b) out4[(size_t)r * D4 + lane] = fnew4[(size_t)b * D4 + lane];
  }
  if (t == 0) *out_ratio = (float)(*count) / (float)Bb;
}

extern "C" void kernel_launch(void* const* d_in, const int* in_sizes, int n_in,
                              void* d_out, int out_size, void* d_ws, size_t ws_size,
                              hipStream_t stream) {
  const float* bank       = (const float*)d_in[0];
  const int*   label_bank = (const int*)  d_in[1];
  const float* cent       = (const float*)d_in[2];
  const int*   ind        = (const int*)  d_in[3];
  const float* feat       = (const float*)d_in[4];
  float* out = (float*)d_out;

  int*   marker   = (int*)d_ws;                  // [Lb]
  int*   newlabel = marker + Lb;                 // [Bb]
  int*   count    = newlabel + Bb;               // [1]
  float* centT    = (float*)(count + 1);         // [Dm*Cc]  1 MB
  float* fnew     = centT + (size_t)Dm * Cc;     // [Bb*Dm] 16 MB

  float* out_lab   = out + (size_t)Lb * Dm;
  float* out_ratio = out_lab + Lb;

  k_pre <<<GPRE, 256, 0, stream>>>((const float4*)feat, (const float4*)bank, ind,
                                   cent, centT, (float4*)fnew, marker, count);
  k_mark<<<Bb / 256, 256, 0, stream>>>(ind, marker);
  k_main<<<GMAIN, 256, 0, stream>>>((const float4*)bank, (const float4*)centT,
                                    (const float4*)fnew, ind, label_bank,
                                    newlabel, count, (float4*)out);
  k_post<<<GPOST, 256, 0, stream>>>((const float4*)fnew, ind, marker, newlabel,
                                    label_bank, count, (float4*)out, out_lab, out_ratio);
}